// Round 4
// baseline (455.291 us; speedup 1.0000x reference)
//
#include <hip/hip_runtime.h>
#include <math.h>

#define N_    4
#define CIN   16
#define COUT  32
#define DD    16
#define HH_   64
#define WW_   64
#define MCNT  262144.0f   // per-channel count: 4*16*64*64

typedef __attribute__((ext_vector_type(8))) short short8;
typedef __attribute__((ext_vector_type(4))) float floatx4;

__device__ __forceinline__ ushort f2bf(float f) {
    uint u = __float_as_uint(f);
    uint r = (u + 0x7fffu + ((u >> 16) & 1u)) >> 16;
    return (ushort)r;
}

// ===================== FAST PATH (bf16 MFMA) =====================
// ws layout (float units):
//   [0, 2162688)            xT bf16 [4n][16d][64h][66 wslot][16 ci]   (4,325,376 u16)
//                           wslot = w+1; slot 0 (w=-1) and slot 65 (w=64) are zeros
//   [2162688, 2171904)      wpair bf16 [9 t9][2 pair][32 co][32 k]    (18,432 u16)
//                           pair0: k<16 -> kw0, k>=16 -> kw1 ; pair1: k<16 -> kw2, k>=16 -> 0
//   [2171904, +128)         stats: sums[32] sumsqs[32] scale[32] shift[32]
#define FAST_XT_F    0
#define FAST_WB_F    2162688
#define FAST_STAT_F  2171904
#define FAST_BYTES   ((size_t)(FAST_STAT_F + 128) * 4)
#define XROW_U16     1056   // 66 slots * 16 ci
#define XROW_U32     528    // 66 slots * 8 u32

// ---- weight preprocessing: soft-threshold + hamming + bf16 paired layout ----
__global__ void prep_weights_mfma(const float* __restrict__ weight,
                                  ushort* __restrict__ wb, float* __restrict__ stats) {
    int t = threadIdx.x;  // 512 threads
    if (t < 64) stats[t] = 0.0f;  // zero sums+sumsqs every call
    int cout = t >> 4, cin = t & 15;
    const float* wp = weight + (cout * CIN + cin) * 27;
    float wv[27];
    float mx = -INFINITY;
    #pragma unroll
    for (int k = 0; k < 27; ++k) { wv[k] = wp[k]; mx = fmaxf(mx, wv[k]); }
    float cutoff = mx * 0.5f;
    const float win[3] = {0.08f, 1.0f, 0.08f};
    #pragma unroll
    for (int k = 0; k < 27; ++k) {
        float w = wv[k];
        float s = (w > 0.0f) ? 1.0f : ((w < 0.0f) ? -1.0f : 0.0f);
        float shr = s * fmaxf(fabsf(w) - cutoff * 0.01f, 0.0f);
        float o = (w < cutoff) ? shr : w;
        int kd = k / 9, kr = k % 9, kh = kr / 3, kw = kr % 3;
        o *= win[kd] * win[kh] * win[kw];
        int t9 = kd * 3 + kh;
        int p  = (kw == 2) ? 1 : 0;
        int kk = p ? cin : (kw * 16 + cin);
        wb[((t9 * 2 + p) * COUT + cout) * 32 + kk] = f2bf(o);
    }
    // zero upper half of pair1 (k = 16..31)
    #pragma unroll
    for (int t9 = 0; t9 < 9; ++t9)
        wb[((t9 * 2 + 1) * COUT + cout) * 32 + 16 + cin] = 0;
}

// ---- x transpose: [n][ci][d][h][w] fp32 -> [n][d][h][wslot][ci] bf16 ----
__global__ __launch_bounds__(256, 4)
void transpose_x(const float* __restrict__ x, ushort* __restrict__ xt) {
    __shared__ ushort lds[4 * 64 * 16];
    int b = blockIdx.x;             // 1024 = n(4) x d(16) x hq(16)
    int n = b >> 8, d = (b >> 4) & 15, h0 = (b & 15) * 4;
    int t = threadIdx.x;
    int hh = t >> 6, w = t & 63;
    const float* xp = x + ((size_t)(n * CIN * DD + d) * HH_ + (h0 + hh)) * WW_ + w;
    const int CSTRIDE = DD * HH_ * WW_;  // 65536
    uint rowv[8];
    #pragma unroll
    for (int cp = 0; cp < 8; ++cp) {
        float a  = xp[(2 * cp)     * CSTRIDE];
        float b2 = xp[(2 * cp + 1) * CSTRIDE];
        rowv[cp] = (uint)f2bf(a) | ((uint)f2bf(b2) << 16);
    }
    #pragma unroll
    for (int cp = 0; cp < 8; ++cp)
        *(uint*)&lds[(hh * 64 + w) * 16 + 2 * cp] = rowv[cp];
    __syncthreads();
    uint* xtg = (uint*)xt;
    for (int i = t; i < 4 * XROW_U32; i += 256) {   // 528 u32 per h-row (66 slots x 8)
        int hh2 = i / XROW_U32, u = i - hh2 * XROW_U32;
        int slot = u >> 3, cp = u & 7;
        uint val = 0;
        if (slot >= 1 && slot <= 64)
            val = *(uint*)&lds[(hh2 * 64 + (slot - 1)) * 16 + 2 * cp];
        xtg[(size_t)((n * DD + d) * HH_ + (h0 + hh2)) * XROW_U32 + u] = val;
    }
}

// ---- conv via MFMA: per wave: 1 h-row, 64 w, 32 co; no LDS ----
__global__ __launch_bounds__(256, 4)
void conv_mfma(const ushort* __restrict__ xt, const ushort* __restrict__ wb,
               const float* __restrict__ bias, float* __restrict__ out,
               float* __restrict__ sums, float* __restrict__ sumsqs) {
    int b = blockIdx.x;             // 1024 = n(4) x d(16) x ht(16)
    int n = b >> 8, d = (b >> 4) & 15, h0 = (b & 15) * 4;
    int t = threadIdx.x;
    int l = t & 63;
    int wv_ = t >> 6;               // wave id -> h row
    int h = h0 + wv_;
    int s = l & 15, g = l >> 4;     // s: spatial col / A-co row ; g: k-group
    int ci0 = (g & 1) * 8;
    int loff0 = (s + (g >> 1)) * 16 + ci0;  // pair0: kw = g>>1 (0 or 1)
    int loff1 = (s + 2) * 16 + ci0;         // pair1: kw = 2 both halves (upper A is 0)
    int k0 = g * 8;

    floatx4 acc[4][2];
    #pragma unroll
    for (int wf = 0; wf < 4; ++wf)
        #pragma unroll
        for (int cf = 0; cf < 2; ++cf)
            acc[wf][cf] = (floatx4){0.f, 0.f, 0.f, 0.f};

    #pragma unroll
    for (int kd = 0; kd < 3; ++kd) {
        int zd = d + kd - 1;
        if ((unsigned)zd >= DD) continue;           // uniform per block
        #pragma unroll
        for (int kh = 0; kh < 3; ++kh) {
            int zh = h + kh - 1;
            if ((unsigned)zh >= HH_) continue;      // uniform per wave
            int t9 = kd * 3 + kh;
            short8 A[2][2];
            #pragma unroll
            for (int p = 0; p < 2; ++p)
                #pragma unroll
                for (int cf = 0; cf < 2; ++cf)
                    A[p][cf] = *(const short8*)&wb[((t9 * 2 + p) * COUT + cf * 16 + s) * 32 + k0];
            const ushort* xrow = xt + (size_t)((n * DD + zd) * HH_ + zh) * XROW_U16;
            #pragma unroll
            for (int p = 0; p < 2; ++p) {
                int lo = p ? loff1 : loff0;
                #pragma unroll
                for (int wf = 0; wf < 4; ++wf) {
                    short8 B = *(const short8*)&xrow[wf * 256 + lo];
                    acc[wf][0] = __builtin_amdgcn_mfma_f32_16x16x32_bf16(A[p][0], B, acc[wf][0], 0, 0, 0);
                    acc[wf][1] = __builtin_amdgcn_mfma_f32_16x16x32_bf16(A[p][1], B, acc[wf][1], 0, 0, 0);
                }
            }
        }
    }

    // epilogue: C layout col = l&15 (=s -> w), row = g*4 + j (-> co within 16)
    float s1[2][4], s2[2][4];
    #pragma unroll
    for (int cf = 0; cf < 2; ++cf)
        #pragma unroll
        for (int j = 0; j < 4; ++j) { s1[cf][j] = 0.f; s2[cf][j] = 0.f; }

    #pragma unroll
    for (int cf = 0; cf < 2; ++cf) {
        #pragma unroll
        for (int j = 0; j < 4; ++j) {
            int co = cf * 16 + g * 4 + j;
            float bval = bias[co];
            size_t obase = ((size_t)(n * COUT + co) * DD + d) * (HH_ * WW_) + h * WW_ + s;
            #pragma unroll
            for (int wf = 0; wf < 4; ++wf) {
                float val = acc[wf][cf][j] + bval;
                out[obase + wf * 16] = val;
                s1[cf][j] += val;
                s2[cf][j] += val * val;
            }
        }
    }
    // reduce over the 16 s-lanes sharing each co
    #pragma unroll
    for (int m = 1; m < 16; m <<= 1) {
        #pragma unroll
        for (int cf = 0; cf < 2; ++cf)
            #pragma unroll
            for (int j = 0; j < 4; ++j) {
                s1[cf][j] += __shfl_xor(s1[cf][j], m);
                s2[cf][j] += __shfl_xor(s2[cf][j], m);
            }
    }
    if (s == 0) {
        #pragma unroll
        for (int cf = 0; cf < 2; ++cf)
            #pragma unroll
            for (int j = 0; j < 4; ++j) {
                int co = cf * 16 + g * 4 + j;
                atomicAdd(&sums[co], s1[cf][j]);
                atomicAdd(&sumsqs[co], s2[cf][j]);
            }
    }
}

// ===================== FALLBACK PATH (fp32 VALU, round-2) =====================
#define WS_W      0
#define WS_SUM    13824
#define WS_SUMSQ  13856
#define WS_SCALE  13888
#define WS_SHIFT  13920

__global__ void prep_weights(const float* __restrict__ weight, float* __restrict__ ws) {
    int t = threadIdx.x;  // 512 threads
    if (t < 64) ws[WS_SUM + t] = 0.0f;
    int cout = t >> 4, cin = t & 15;
    const float* wp = weight + (cout * CIN + cin) * 27;
    float wv[27];
    float mx = -INFINITY;
    #pragma unroll
    for (int k = 0; k < 27; ++k) { wv[k] = wp[k]; mx = fmaxf(mx, wv[k]); }
    float cutoff = mx * 0.5f;
    const float win[3] = {0.08f, 1.0f, 0.08f};
    #pragma unroll
    for (int k = 0; k < 27; ++k) {
        float w = wv[k];
        float s = (w > 0.0f) ? 1.0f : ((w < 0.0f) ? -1.0f : 0.0f);
        float shr = s * fmaxf(fabsf(w) - cutoff * 0.01f, 0.0f);
        float o = (w < cutoff) ? shr : w;
        int kd = k / 9, kr = k % 9, kh = kr / 3, kw = kr % 3;
        o *= win[kd] * win[kh] * win[kw];
        ws[WS_W + (cin * 27 + k) * COUT + cout] = o;
    }
}

#define RS 68
__global__ __launch_bounds__(256, 4)
void conv_kernel(const float* __restrict__ x, const float* __restrict__ bias,
                 const float* __restrict__ wsw, float* __restrict__ out,
                 float* __restrict__ sums, float* __restrict__ sumsqs) {
    __shared__ float xs[3 * 6 * RS];
    __shared__ float sred[16][8];
    int b = blockIdx.x;
    int n  = b >> 8;
    int d  = (b >> 4) & 15;
    int h0 = (b & 15) << 2;
    int tid = threadIdx.x;
    int wg = tid & 15;
    int cg = (tid >> 4) & 3;
    int v  = tid >> 6;
    int cohalf = v & 1;
    int hhalf  = v >> 1;
    int w0 = wg * 4;
    int co0 = cohalf * 16 + cg * 4;
    float acc[4][2][4];
    #pragma unroll
    for (int c = 0; c < 4; ++c)
        #pragma unroll
        for (int i = 0; i < 2; ++i)
            #pragma unroll
            for (int j = 0; j < 4; ++j) acc[c][i][j] = 0.0f;
    const float* xn = x + (size_t)n * CIN * DD * HH_ * WW_;
    for (int cin = 0; cin < CIN; ++cin) {
        __syncthreads();
        const float* xc = xn + cin * DD * HH_ * WW_;
        for (int idx = tid; idx < 3 * 6 * RS; idx += 256) {
            int row = idx / RS;
            int c   = idx - row * RS;
            int dd  = row / 6;
            int r   = row - dd * 6;
            int zd = d - 1 + dd;
            int zh = h0 - 1 + r;
            int w  = c - 1;
            float val = 0.0f;
            if ((unsigned)zd < DD && (unsigned)zh < HH_ && (unsigned)w < WW_)
                val = xc[(zd * HH_ + zh) * WW_ + w];
            xs[idx] = val;
        }
        __syncthreads();
        const float* wc = wsw + cin * 27 * COUT + co0;
        #pragma unroll 1
        for (int kd = 0; kd < 3; ++kd) {
            float4 wvv[9];
            #pragma unroll
            for (int j = 0; j < 9; ++j)
                wvv[j] = *(const float4*)&wc[(kd * 9 + j) * COUT];
            const float* xp = &xs[(kd * 6 + hhalf * 2) * RS];
            #pragma unroll
            for (int rr = 0; rr < 4; ++rr) {
                const float* xr_ = &xp[rr * RS + w0];
                float4 xm = *(const float4*)xr_;
                float x4 = xr_[4];
                float x5 = xr_[5];
                float xv[6] = {xm.x, xm.y, xm.z, xm.w, x4, x5};
                #pragma unroll
                for (int kh = 0; kh < 3; ++kh) {
                    int i = rr - kh;
                    if (i < 0 || i > 1) continue;
                    #pragma unroll
                    for (int kw = 0; kw < 3; ++kw) {
                        float4 w4 = wvv[kh * 3 + kw];
                        #pragma unroll
                        for (int j = 0; j < 4; ++j) {
                            float xx = xv[j + kw];
                            acc[0][i][j] = fmaf(w4.x, xx, acc[0][i][j]);
                            acc[1][i][j] = fmaf(w4.y, xx, acc[1][i][j]);
                            acc[2][i][j] = fmaf(w4.z, xx, acc[2][i][j]);
                            acc[3][i][j] = fmaf(w4.w, xx, acc[3][i][j]);
                        }
                    }
                }
            }
        }
    }
    float s1[4], s2[4];
    #pragma unroll
    for (int c = 0; c < 4; ++c) {
        float bval = bias[co0 + c];
        s1[c] = 0.0f; s2[c] = 0.0f;
        #pragma unroll
        for (int i = 0; i < 2; ++i) {
            float4 o;
            float* op = (float*)&o;
            #pragma unroll
            for (int j = 0; j < 4; ++j) {
                float val = acc[c][i][j] + bval;
                op[j] = val;
                s1[c] += val;
                s2[c] += val * val;
            }
            int h = h0 + hhalf * 2 + i;
            *(float4*)&out[((((size_t)n * COUT + co0 + c) * DD + d) * HH_ + h) * WW_ + w0] = o;
        }
    }
    #pragma unroll
    for (int m = 1; m < 16; m <<= 1) {
        #pragma unroll
        for (int c = 0; c < 4; ++c) {
            s1[c] += __shfl_xor(s1[c], m);
            s2[c] += __shfl_xor(s2[c], m);
        }
    }
    if ((tid & 15) == 0) {
        int gg = tid >> 4;
        #pragma unroll
        for (int c = 0; c < 4; ++c) { sred[gg][c] = s1[c]; sred[gg][4 + c] = s2[c]; }
    }
    __syncthreads();
    if (tid < 64) {
        int co   = tid & 31;
        int kind = tid >> 5;
        int ch   = (co >> 4) & 1;
        int cgg  = (co >> 2) & 3;
        int c    = co & 3;
        float val = sred[ch * 4 + cgg][kind * 4 + c] + sred[(ch + 2) * 4 + cgg][kind * 4 + c];
        atomicAdd(kind ? &sumsqs[co] : &sums[co], val);
    }
}

// ===================== SHARED EPILOGUE KERNELS =====================
__global__ void stats_kernel(const float* __restrict__ gamma, const float* __restrict__ beta,
                             const float* __restrict__ sums, const float* __restrict__ sumsqs,
                             float* __restrict__ scale, float* __restrict__ shift) {
    int c = threadIdx.x;
    if (c >= 32) return;
    float mean = sums[c] / MCNT;
    float var  = sumsqs[c] / MCNT - mean * mean;
    float rstd = rsqrtf(var + 1e-5f);
    float sc = gamma[c] * rstd;
    scale[c] = sc;
    shift[c] = beta[c] - mean * sc;
}

__global__ void bn_act_kernel(float* __restrict__ out, const float* __restrict__ scale,
                              const float* __restrict__ shift) {
    const int NV4 = (N_ * COUT * DD * HH_ * WW_) / 4;
    int stride = gridDim.x * blockDim.x;
    float4* o4 = (float4*)out;
    for (int i = blockIdx.x * blockDim.x + threadIdx.x; i < NV4; i += stride) {
        int ch = (i >> 14) & 31;
        float sc = scale[ch];
        float sh = shift[ch];
        float4 val = o4[i];
        float* vp = (float*)&val;
        #pragma unroll
        for (int j = 0; j < 4; ++j) {
            float z = vp[j] * sc + sh;
            vp[j] = fmaxf(z, 0.0f) + log1pf(expf(-fabsf(z)));
        }
        o4[i] = val;
    }
}

extern "C" void kernel_launch(void* const* d_in, const int* in_sizes, int n_in,
                              void* d_out, int out_size, void* d_ws, size_t ws_size,
                              hipStream_t stream) {
    const float* x      = (const float*)d_in[0];
    const float* weight = (const float*)d_in[1];
    const float* bias   = (const float*)d_in[2];
    const float* gamma  = (const float*)d_in[3];
    const float* beta   = (const float*)d_in[4];
    float* out = (float*)d_out;
    float* wsf = (float*)d_ws;

    if (ws_size >= FAST_BYTES) {
        ushort* xt    = (ushort*)(wsf + FAST_XT_F);
        ushort* wb    = (ushort*)(wsf + FAST_WB_F);
        float*  stats = wsf + FAST_STAT_F;
        float*  sums   = stats;
        float*  sumsqs = stats + 32;
        float*  scale  = stats + 64;
        float*  shift  = stats + 96;
        hipLaunchKernelGGL(prep_weights_mfma, dim3(1), dim3(512), 0, stream, weight, wb, stats);
        hipLaunchKernelGGL(transpose_x, dim3(1024), dim3(256), 0, stream, x, xt);
        hipLaunchKernelGGL(conv_mfma, dim3(1024), dim3(256), 0, stream,
                           xt, wb, bias, out, sums, sumsqs);
        hipLaunchKernelGGL(stats_kernel, dim3(1), dim3(64), 0, stream,
                           gamma, beta, sums, sumsqs, scale, shift);
        hipLaunchKernelGGL(bn_act_kernel, dim3(2048), dim3(256), 0, stream, out, scale, shift);
    } else {
        hipLaunchKernelGGL(prep_weights, dim3(1), dim3(512), 0, stream, weight, wsf);
        hipLaunchKernelGGL(conv_kernel, dim3(1024), dim3(256), 0, stream,
                           x, bias, wsf + WS_W, out, wsf + WS_SUM, wsf + WS_SUMSQ);
        hipLaunchKernelGGL(stats_kernel, dim3(1), dim3(64), 0, stream,
                           gamma, beta, wsf + WS_SUM, wsf + WS_SUMSQ, wsf + WS_SCALE, wsf + WS_SHIFT);
        hipLaunchKernelGGL(bn_act_kernel, dim3(2048), dim3(256), 0, stream,
                           out, wsf + WS_SCALE, wsf + WS_SHIFT);
    }
}

// Round 5
// 78.570 us; speedup vs baseline: 5.7947x; 5.7947x over previous
//
#include <hip/hip_runtime.h>
#include <math.h>

#define N_    4
#define CIN   16
#define COUT  32
#define DD    16
#define HH_   64
#define WW_   64
#define MCNT  262144.0f   // per-channel count: 4*16*64*64

typedef __attribute__((ext_vector_type(8))) short short8;
typedef __attribute__((ext_vector_type(4))) float floatx4;

__device__ __forceinline__ ushort f2bf(float f) {
    uint u = __float_as_uint(f);
    uint r = (u + 0x7fffu + ((u >> 16) & 1u)) >> 16;
    return (ushort)r;
}

// ===================== FAST PATH (bf16 MFMA) =====================
// ws layout (float units):
//   [0, 2162688)            xT bf16 [4n][16d][64h][66 wslot][16 ci]   (4,325,376 u16)
//                           wslot = w+1; slot 0 (w=-1) and slot 65 (w=64) are zeros
//   [2162688, 2171904)      wpair bf16 [9 t9][2 pair][32 co][32 k]    (18,432 u16)
//                           pair0: k<16 -> kw0, k>=16 -> kw1 ; pair1: k<16 -> kw2, k>=16 -> 0
//   [2171904, +128)         stats: sums[32] sumsqs[32] scale[32] shift[32]
#define FAST_XT_F    0
#define FAST_WB_F    2162688
#define FAST_STAT_F  2171904
#define FAST_BYTES   ((size_t)(FAST_STAT_F + 128) * 4)
#define XROW_U16     1056   // 66 slots * 16 ci
#define XROW_CHUNKS  132    // 16B chunks per row

// ---- weight preprocessing: soft-threshold + hamming + bf16 paired layout ----
__global__ void prep_weights_mfma(const float* __restrict__ weight,
                                  ushort* __restrict__ wb, float* __restrict__ stats) {
    int t = threadIdx.x;  // 512 threads
    if (t < 64) stats[t] = 0.0f;  // zero sums+sumsqs every call
    int cout = t >> 4, cin = t & 15;
    const float* wp = weight + (cout * CIN + cin) * 27;
    float wv[27];
    float mx = -INFINITY;
    #pragma unroll
    for (int k = 0; k < 27; ++k) { wv[k] = wp[k]; mx = fmaxf(mx, wv[k]); }
    float cutoff = mx * 0.5f;
    const float win[3] = {0.08f, 1.0f, 0.08f};
    #pragma unroll
    for (int k = 0; k < 27; ++k) {
        float w = wv[k];
        float s = (w > 0.0f) ? 1.0f : ((w < 0.0f) ? -1.0f : 0.0f);
        float shr = s * fmaxf(fabsf(w) - cutoff * 0.01f, 0.0f);
        float o = (w < cutoff) ? shr : w;
        int kd = k / 9, kr = k % 9, kh = kr / 3, kw = kr % 3;
        o *= win[kd] * win[kh] * win[kw];
        int t9 = kd * 3 + kh;
        int p  = (kw == 2) ? 1 : 0;
        int kk = p ? cin : (kw * 16 + cin);
        wb[((t9 * 2 + p) * COUT + cout) * 32 + kk] = f2bf(o);
    }
    // zero upper half of pair1 (k = 16..31)
    #pragma unroll
    for (int t9 = 0; t9 < 9; ++t9)
        wb[((t9 * 2 + 1) * COUT + cout) * 32 + 16 + cin] = 0;
}

// ---- x transpose: [n][ci][d][h][w] fp32 -> [n][d][h][wslot][ci] bf16 ----
__global__ __launch_bounds__(256, 4)
void transpose_x(const float* __restrict__ x, ushort* __restrict__ xt) {
    __shared__ ushort lds[4 * 64 * 16];
    int b = blockIdx.x;             // 1024 = n(4) x d(16) x hq(16)
    int n = b >> 8, d = (b >> 4) & 15, h0 = (b & 15) * 4;
    int t = threadIdx.x;
    int hh = t >> 6, w = t & 63;
    const float* xp = x + ((size_t)(n * CIN * DD + d) * HH_ + (h0 + hh)) * WW_ + w;
    const int CSTRIDE = DD * HH_ * WW_;  // 65536
    uint rowv[8];
    #pragma unroll
    for (int cp = 0; cp < 8; ++cp) {
        float a  = xp[(2 * cp)     * CSTRIDE];
        float b2 = xp[(2 * cp + 1) * CSTRIDE];
        rowv[cp] = (uint)f2bf(a) | ((uint)f2bf(b2) << 16);
    }
    #pragma unroll
    for (int cp = 0; cp < 8; ++cp)
        *(uint*)&lds[(hh * 64 + w) * 16 + 2 * cp] = rowv[cp];
    __syncthreads();
    uint* xtg = (uint*)xt;
    for (int i = t; i < 4 * 528; i += 256) {   // 528 u32 per h-row (66 slots x 8)
        int hh2 = i / 528, u = i - hh2 * 528;
        int slot = u >> 3, cp = u & 7;
        uint val = 0;
        if (slot >= 1 && slot <= 64)
            val = *(uint*)&lds[(hh2 * 64 + (slot - 1)) * 16 + 2 * cp];
        xtg[(size_t)((n * DD + d) * HH_ + (h0 + hh2)) * 528 + u] = val;
    }
}

// ---- conv via MFMA: bulk-stage weights + x-halo in LDS, then pure LDS+MFMA loop ----
// Block: n(4) x d(16) x ht(16 tiles of 4 h). Wave wv_ owns h = h0+wv_.
// Lane: s = l&15 (spatial w within 16-group / A co row), g = l>>4 (k-group).
__global__ __launch_bounds__(256, 2)
void conv_mfma(const ushort* __restrict__ xt, const ushort* __restrict__ wb,
               const float* __restrict__ bias, float* __restrict__ out,
               float* __restrict__ sums, float* __restrict__ sumsqs) {
    __shared__ ushort wlds[9 * 2 * COUT * 32];    // 36864 B
    __shared__ ushort xs[3 * 6 * XROW_U16];       // 38016 B: [zdi][rh][66 slot][16 ci]
    __shared__ float sred[4][64];

    int b = blockIdx.x;             // 1024 = n(4) x d(16) x ht(16)
    int n = b >> 8, d = (b >> 4) & 15, h0 = (b & 15) * 4;
    int t = threadIdx.x;
    int l = t & 63;
    int wv_ = t >> 6;               // wave id -> h row
    int h = h0 + wv_;
    int s = l & 15, g = l >> 4;

    // ---- stage weights: 2304 x 16B ----
    const uint4* wb4 = (const uint4*)wb;
    uint4* wl4 = (uint4*)wlds;
    #pragma unroll 3
    for (int i = t; i < 2304; i += 256) wl4[i] = wb4[i];

    // ---- stage x halo: 18 rows x 132 chunks, OOB rows -> zeros ----
    const uint4* xt4 = (const uint4*)xt;
    uint4* xs4 = (uint4*)xs;
    #pragma unroll 3
    for (int i = t; i < 18 * XROW_CHUNKS; i += 256) {
        int row = i / XROW_CHUNKS, c = i - row * XROW_CHUNKS;
        int zdi = row / 6, rh = row - zdi * 6;
        int zd = d - 1 + zdi, zh = h0 - 1 + rh;
        uint4 v = {0u, 0u, 0u, 0u};
        if ((unsigned)zd < DD && (unsigned)zh < HH_)
            v = xt4[(size_t)((n * DD + zd) * HH_ + zh) * XROW_CHUNKS + c];
        xs4[i] = v;
    }
    __syncthreads();

    floatx4 acc[4][2];
    #pragma unroll
    for (int wf = 0; wf < 4; ++wf)
        #pragma unroll
        for (int cf = 0; cf < 2; ++cf)
            acc[wf][cf] = (floatx4){0.f, 0.f, 0.f, 0.f};

    int lo0 = (s + (g >> 1)) * 16 + (g & 1) * 8;  // pair0: kw = g>>1
    int lo1 = (s + 2) * 16 + (g & 1) * 8;         // pair1: kw = 2
    int k0 = g * 8;

    #pragma unroll
    for (int kd = 0; kd < 3; ++kd) {
        #pragma unroll
        for (int kh = 0; kh < 3; ++kh) {
            int t9 = kd * 3 + kh;
            short8 A[2][2];
            #pragma unroll
            for (int p = 0; p < 2; ++p)
                #pragma unroll
                for (int cf = 0; cf < 2; ++cf)
                    A[p][cf] = *(const short8*)&wlds[((t9 * 2 + p) * COUT + cf * 16 + s) * 32 + k0];
            const ushort* xrow = &xs[(kd * 6 + wv_ + kh) * XROW_U16];
            #pragma unroll
            for (int p = 0; p < 2; ++p) {
                int lo = p ? lo1 : lo0;
                #pragma unroll
                for (int wf = 0; wf < 4; ++wf) {
                    short8 B = *(const short8*)&xrow[wf * 256 + lo];
                    acc[wf][0] = __builtin_amdgcn_mfma_f32_16x16x32_bf16(A[p][0], B, acc[wf][0], 0, 0, 0);
                    acc[wf][1] = __builtin_amdgcn_mfma_f32_16x16x32_bf16(A[p][1], B, acc[wf][1], 0, 0, 0);
                }
            }
        }
    }

    // epilogue: C layout col = s -> w, row = g*4 + j -> co (within cf half)
    float s1[2][4], s2[2][4];
    #pragma unroll
    for (int cf = 0; cf < 2; ++cf)
        #pragma unroll
        for (int j = 0; j < 4; ++j) { s1[cf][j] = 0.f; s2[cf][j] = 0.f; }

    #pragma unroll
    for (int cf = 0; cf < 2; ++cf) {
        #pragma unroll
        for (int j = 0; j < 4; ++j) {
            int co = cf * 16 + g * 4 + j;
            float bval = bias[co];
            size_t obase = ((size_t)(n * COUT + co) * DD + d) * (HH_ * WW_) + h * WW_ + s;
            #pragma unroll
            for (int wf = 0; wf < 4; ++wf) {
                float val = acc[wf][cf][j] + bval;
                out[obase + wf * 16] = val;
                s1[cf][j] += val;
                s2[cf][j] += val * val;
            }
        }
    }
    // reduce over 16 s-lanes sharing each co
    #pragma unroll
    for (int m = 1; m < 16; m <<= 1) {
        #pragma unroll
        for (int cf = 0; cf < 2; ++cf)
            #pragma unroll
            for (int j = 0; j < 4; ++j) {
                s1[cf][j] += __shfl_xor(s1[cf][j], m);
                s2[cf][j] += __shfl_xor(s2[cf][j], m);
            }
    }
    if (s == 0) {
        #pragma unroll
        for (int cf = 0; cf < 2; ++cf)
            #pragma unroll
            for (int j = 0; j < 4; ++j) {
                int co = cf * 16 + g * 4 + j;
                sred[wv_][co]      = s1[cf][j];
                sred[wv_][32 + co] = s2[cf][j];
            }
    }
    __syncthreads();
    if (t < 64) {
        float v = sred[0][t] + sred[1][t] + sred[2][t] + sred[3][t];
        atomicAdd(t < 32 ? &sums[t] : &sumsqs[t - 32], v);
    }
}

// ===================== FALLBACK PATH (fp32 VALU, round-2) =====================
#define WS_W      0
#define WS_SUM    13824
#define WS_SUMSQ  13856
#define WS_SCALE  13888
#define WS_SHIFT  13920

__global__ void prep_weights(const float* __restrict__ weight, float* __restrict__ ws) {
    int t = threadIdx.x;  // 512 threads
    if (t < 64) ws[WS_SUM + t] = 0.0f;
    int cout = t >> 4, cin = t & 15;
    const float* wp = weight + (cout * CIN + cin) * 27;
    float wv[27];
    float mx = -INFINITY;
    #pragma unroll
    for (int k = 0; k < 27; ++k) { wv[k] = wp[k]; mx = fmaxf(mx, wv[k]); }
    float cutoff = mx * 0.5f;
    const float win[3] = {0.08f, 1.0f, 0.08f};
    #pragma unroll
    for (int k = 0; k < 27; ++k) {
        float w = wv[k];
        float s = (w > 0.0f) ? 1.0f : ((w < 0.0f) ? -1.0f : 0.0f);
        float shr = s * fmaxf(fabsf(w) - cutoff * 0.01f, 0.0f);
        float o = (w < cutoff) ? shr : w;
        int kd = k / 9, kr = k % 9, kh = kr / 3, kw = kr % 3;
        o *= win[kd] * win[kh] * win[kw];
        ws[WS_W + (cin * 27 + k) * COUT + cout] = o;
    }
}

#define RS 68
__global__ __launch_bounds__(256, 4)
void conv_kernel(const float* __restrict__ x, const float* __restrict__ bias,
                 const float* __restrict__ wsw, float* __restrict__ out,
                 float* __restrict__ sums, float* __restrict__ sumsqs) {
    __shared__ float xsf[3 * 6 * RS];
    __shared__ float sred[16][8];
    int b = blockIdx.x;
    int n  = b >> 8;
    int d  = (b >> 4) & 15;
    int h0 = (b & 15) << 2;
    int tid = threadIdx.x;
    int wg = tid & 15;
    int cg = (tid >> 4) & 3;
    int v  = tid >> 6;
    int cohalf = v & 1;
    int hhalf  = v >> 1;
    int w0 = wg * 4;
    int co0 = cohalf * 16 + cg * 4;
    float acc[4][2][4];
    #pragma unroll
    for (int c = 0; c < 4; ++c)
        #pragma unroll
        for (int i = 0; i < 2; ++i)
            #pragma unroll
            for (int j = 0; j < 4; ++j) acc[c][i][j] = 0.0f;
    const float* xn = x + (size_t)n * CIN * DD * HH_ * WW_;
    for (int cin = 0; cin < CIN; ++cin) {
        __syncthreads();
        const float* xc = xn + cin * DD * HH_ * WW_;
        for (int idx = tid; idx < 3 * 6 * RS; idx += 256) {
            int row = idx / RS;
            int c   = idx - row * RS;
            int dd  = row / 6;
            int r   = row - dd * 6;
            int zd = d - 1 + dd;
            int zh = h0 - 1 + r;
            int w  = c - 1;
            float val = 0.0f;
            if ((unsigned)zd < DD && (unsigned)zh < HH_ && (unsigned)w < WW_)
                val = xc[(zd * HH_ + zh) * WW_ + w];
            xsf[idx] = val;
        }
        __syncthreads();
        const float* wc = wsw + cin * 27 * COUT + co0;
        #pragma unroll 1
        for (int kd = 0; kd < 3; ++kd) {
            float4 wvv[9];
            #pragma unroll
            for (int j = 0; j < 9; ++j)
                wvv[j] = *(const float4*)&wc[(kd * 9 + j) * COUT];
            const float* xp = &xsf[(kd * 6 + hhalf * 2) * RS];
            #pragma unroll
            for (int rr = 0; rr < 4; ++rr) {
                const float* xr_ = &xp[rr * RS + w0];
                float4 xm = *(const float4*)xr_;
                float x4 = xr_[4];
                float x5 = xr_[5];
                float xv[6] = {xm.x, xm.y, xm.z, xm.w, x4, x5};
                #pragma unroll
                for (int kh = 0; kh < 3; ++kh) {
                    int i = rr - kh;
                    if (i < 0 || i > 1) continue;
                    #pragma unroll
                    for (int kw = 0; kw < 3; ++kw) {
                        float4 w4 = wvv[kh * 3 + kw];
                        #pragma unroll
                        for (int j = 0; j < 4; ++j) {
                            float xx = xv[j + kw];
                            acc[0][i][j] = fmaf(w4.x, xx, acc[0][i][j]);
                            acc[1][i][j] = fmaf(w4.y, xx, acc[1][i][j]);
                            acc[2][i][j] = fmaf(w4.z, xx, acc[2][i][j]);
                            acc[3][i][j] = fmaf(w4.w, xx, acc[3][i][j]);
                        }
                    }
                }
            }
        }
    }
    float s1[4], s2[4];
    #pragma unroll
    for (int c = 0; c < 4; ++c) {
        float bval = bias[co0 + c];
        s1[c] = 0.0f; s2[c] = 0.0f;
        #pragma unroll
        for (int i = 0; i < 2; ++i) {
            float4 o;
            float* op = (float*)&o;
            #pragma unroll
            for (int j = 0; j < 4; ++j) {
                float val = acc[c][i][j] + bval;
                op[j] = val;
                s1[c] += val;
                s2[c] += val * val;
            }
            int hh = h0 + hhalf * 2 + i;
            *(float4*)&out[((((size_t)n * COUT + co0 + c) * DD + d) * HH_ + hh) * WW_ + w0] = o;
        }
    }
    #pragma unroll
    for (int m = 1; m < 16; m <<= 1) {
        #pragma unroll
        for (int c = 0; c < 4; ++c) {
            s1[c] += __shfl_xor(s1[c], m);
            s2[c] += __shfl_xor(s2[c], m);
        }
    }
    if ((tid & 15) == 0) {
        int gg = tid >> 4;
        #pragma unroll
        for (int c = 0; c < 4; ++c) { sred[gg][c] = s1[c]; sred[gg][4 + c] = s2[c]; }
    }
    __syncthreads();
    if (tid < 64) {
        int co   = tid & 31;
        int kind = tid >> 5;
        int ch   = (co >> 4) & 1;
        int cgg  = (co >> 2) & 3;
        int c    = co & 3;
        float val = sred[ch * 4 + cgg][kind * 4 + c] + sred[(ch + 2) * 4 + cgg][kind * 4 + c];
        atomicAdd(kind ? &sumsqs[co] : &sums[co], val);
    }
}

// ===================== SHARED EPILOGUE KERNELS =====================
__global__ void stats_kernel(const float* __restrict__ gamma, const float* __restrict__ beta,
                             const float* __restrict__ sums, const float* __restrict__ sumsqs,
                             float* __restrict__ scale, float* __restrict__ shift) {
    int c = threadIdx.x;
    if (c >= 32) return;
    float mean = sums[c] / MCNT;
    float var  = sumsqs[c] / MCNT - mean * mean;
    float rstd = rsqrtf(var + 1e-5f);
    float sc = gamma[c] * rstd;
    scale[c] = sc;
    shift[c] = beta[c] - mean * sc;
}

__global__ void bn_act_kernel(float* __restrict__ out, const float* __restrict__ scale,
                              const float* __restrict__ shift) {
    const int NV4 = (N_ * COUT * DD * HH_ * WW_) / 4;
    int stride = gridDim.x * blockDim.x;
    float4* o4 = (float4*)out;
    for (int i = blockIdx.x * blockDim.x + threadIdx.x; i < NV4; i += stride) {
        int ch = (i >> 14) & 31;
        float sc = scale[ch];
        float sh = shift[ch];
        float4 val = o4[i];
        float* vp = (float*)&val;
        #pragma unroll
        for (int j = 0; j < 4; ++j) {
            float z = vp[j] * sc + sh;
            vp[j] = fmaxf(z, 0.0f) + log1pf(expf(-fabsf(z)));
        }
        o4[i] = val;
    }
}

extern "C" void kernel_launch(void* const* d_in, const int* in_sizes, int n_in,
                              void* d_out, int out_size, void* d_ws, size_t ws_size,
                              hipStream_t stream) {
    const float* x      = (const float*)d_in[0];
    const float* weight = (const float*)d_in[1];
    const float* bias   = (const float*)d_in[2];
    const float* gamma  = (const float*)d_in[3];
    const float* beta   = (const float*)d_in[4];
    float* out = (float*)d_out;
    float* wsf = (float*)d_ws;

    if (ws_size >= FAST_BYTES) {
        ushort* xt    = (ushort*)(wsf + FAST_XT_F);
        ushort* wb    = (ushort*)(wsf + FAST_WB_F);
        float*  stats = wsf + FAST_STAT_F;
        float*  sums   = stats;
        float*  sumsqs = stats + 32;
        float*  scale  = stats + 64;
        float*  shift  = stats + 96;
        hipLaunchKernelGGL(prep_weights_mfma, dim3(1), dim3(512), 0, stream, weight, wb, stats);
        hipLaunchKernelGGL(transpose_x, dim3(1024), dim3(256), 0, stream, x, xt);
        hipLaunchKernelGGL(conv_mfma, dim3(1024), dim3(256), 0, stream,
                           xt, wb, bias, out, sums, sumsqs);
        hipLaunchKernelGGL(stats_kernel, dim3(1), dim3(64), 0, stream,
                           gamma, beta, sums, sumsqs, scale, shift);
        hipLaunchKernelGGL(bn_act_kernel, dim3(2048), dim3(256), 0, stream, out, scale, shift);
    } else {
        hipLaunchKernelGGL(prep_weights, dim3(1), dim3(512), 0, stream, weight, wsf);
        hipLaunchKernelGGL(conv_kernel, dim3(1024), dim3(256), 0, stream,
                           x, bias, wsf + WS_W, out, wsf + WS_SUM, wsf + WS_SUMSQ);
        hipLaunchKernelGGL(stats_kernel, dim3(1), dim3(64), 0, stream,
                           gamma, beta, wsf + WS_SUM, wsf + WS_SUMSQ, wsf + WS_SCALE, wsf + WS_SHIFT);
        hipLaunchKernelGGL(bn_act_kernel, dim3(2048), dim3(256), 0, stream,
                           out, wsf + WS_SCALE, wsf + WS_SHIFT);
    }
}

// Round 7
// 77.833 us; speedup vs baseline: 5.8496x; 1.0095x over previous
//
#include <hip/hip_runtime.h>
#include <math.h>

#define N_    4
#define CIN   16
#define COUT  32
#define DD    16
#define HH_   64
#define WW_   64
#define MCNT  262144.0f   // per-channel count: 4*16*64*64

typedef __attribute__((ext_vector_type(8))) short short8;
typedef __attribute__((ext_vector_type(4))) float floatx4;

__device__ __forceinline__ ushort f2bf(float f) {
    uint u = __float_as_uint(f);
    uint r = (u + 0x7fffu + ((u >> 16) & 1u)) >> 16;
    return (ushort)r;
}

// ===================== FAST PATH (bf16 MFMA) =====================
// ws layout (float units):
//   [0, 2162688)            xT bf16 [4n][16d][64h][66 wslot][16 ci]  (4,325,376 u16)
//                           wslot = w+1; slots 0 and 65 are zeros
//   [2162688, 2169856)      wpk bf16 [14 grp][32 co][32 k]           (14,336 u16)
//                           group g packs (tap,kw) combos q=2g (k<16) and q=2g+1 (k>=16);
//                           q = (kd*3+kh)*3+kw; grp 13 upper half = zeros
//   [2169856, +128)         stats: sums[32] sumsqs[32] scale[32] shift[32]
#define FAST_XT_F    0
#define FAST_WB_F    2162688
#define FAST_STAT_F  2169856
#define FAST_BYTES   ((size_t)(FAST_STAT_F + 128) * 4)
#define XROW_U16     1056   // 66 slots * 16 ci
#define XROW_CHUNKS  132    // 16B chunks per row

// ---- weight preprocessing: soft-threshold + hamming + packed bf16 layout ----
__global__ void prep_weights_mfma(const float* __restrict__ weight,
                                  ushort* __restrict__ wb, float* __restrict__ stats) {
    int t = threadIdx.x;  // 512 threads
    if (t < 64) stats[t] = 0.0f;  // zero sums+sumsqs every call
    int cout = t >> 4, cin = t & 15;
    const float* wp = weight + (cout * CIN + cin) * 27;
    float wv[27];
    float mx = -INFINITY;
    #pragma unroll
    for (int k = 0; k < 27; ++k) { wv[k] = wp[k]; mx = fmaxf(mx, wv[k]); }
    float cutoff = mx * 0.5f;
    const float win[3] = {0.08f, 1.0f, 0.08f};
    #pragma unroll
    for (int k = 0; k < 27; ++k) {
        float w = wv[k];
        float s = (w > 0.0f) ? 1.0f : ((w < 0.0f) ? -1.0f : 0.0f);
        float shr = s * fmaxf(fabsf(w) - cutoff * 0.01f, 0.0f);
        float o = (w < cutoff) ? shr : w;
        int kd = k / 9, kr = k % 9, kh = kr / 3, kw = kr % 3;
        o *= win[kd] * win[kh] * win[kw];
        int q = (kd * 3 + kh) * 3 + kw;       // 0..26
        int grp = q >> 1, half = q & 1;
        wb[(grp * COUT + cout) * 32 + half * 16 + cin] = f2bf(o);
    }
    // zero upper half of group 13
    wb[(13 * COUT + cout) * 32 + 16 + cin] = 0;
}

// ---- x transpose: [n][ci][d][h][w] fp32 -> [n][d][h][wslot][ci] bf16 ----
__global__ __launch_bounds__(256, 4)
void transpose_x(const float* __restrict__ x, ushort* __restrict__ xt) {
    __shared__ ushort lds[4 * 64 * 16];
    int b = blockIdx.x;             // 1024 = n(4) x d(16) x hq(16)
    int n = b >> 8, d = (b >> 4) & 15, h0 = (b & 15) * 4;
    int t = threadIdx.x;
    int hh = t >> 6, w = t & 63;
    const float* xp = x + ((size_t)(n * CIN * DD + d) * HH_ + (h0 + hh)) * WW_ + w;
    const int CSTRIDE = DD * HH_ * WW_;  // 65536
    uint rowv[8];
    #pragma unroll
    for (int cp = 0; cp < 8; ++cp) {
        float a  = xp[(2 * cp)     * CSTRIDE];
        float b2 = xp[(2 * cp + 1) * CSTRIDE];
        rowv[cp] = (uint)f2bf(a) | ((uint)f2bf(b2) << 16);
    }
    #pragma unroll
    for (int cp = 0; cp < 8; ++cp)
        *(uint*)&lds[(hh * 64 + w) * 16 + 2 * cp] = rowv[cp];
    __syncthreads();
    uint* xtg = (uint*)xt;
    for (int i = t; i < 4 * 528; i += 256) {   // 528 u32 per h-row (66 slots x 8)
        int hh2 = i / 528, u = i - hh2 * 528;
        int slot = u >> 3, cp = u & 7;
        uint val = 0;
        if (slot >= 1 && slot <= 64)
            val = *(uint*)&lds[(hh2 * 64 + (slot - 1)) * 16 + 2 * cp];
        xtg[(size_t)((n * DD + d) * HH_ + (h0 + hh2)) * 528 + u] = val;
    }
}

// ---- conv via MFMA: A in registers (cf-split waves), x tile in LDS ----
// Grid: 1024 = n(4) x d(16) x ht(16 tiles of 4 h). Block: 512 threads, 8 waves.
// Wave wv = (hq<<1)|cf: h = h0+hq, couts cf*16..cf*16+15.
// Lane: s = l&15 (w within 16-group / A co row), g = l>>4 (k-group).
__global__ __launch_bounds__(512, 4)
void conv_mfma(const ushort* __restrict__ xt, const ushort* __restrict__ wb,
               const float* __restrict__ bias, float* __restrict__ out,
               float* __restrict__ sums, float* __restrict__ sumsqs) {
    __shared__ ushort xs[3 * 6 * XROW_U16];   // 38016 B: [zdi][rh][66 slot][16 ci]
    __shared__ float sred[8][64];

    int b = blockIdx.x;
    int n = b >> 8, d = (b >> 4) & 15, h0 = (b & 15) * 4;
    int t = threadIdx.x;
    int l = t & 63;
    int wv_ = t >> 6;
    int hq = wv_ >> 1, cf = wv_ & 1;
    int h = h0 + hq;
    int s = l & 15, g = l >> 4;
    int ghi = g >> 1;                // 0: k<16 half, 1: k>=16 half

    // zero sred (each wave writes only its cf-half later; reader must see 0 elsewhere)
    ((float*)sred)[t] = 0.0f;

    // ---- A fragments: 14 x 16B from global (L2-hot 28.7 KB) ----
    short8 A[14];
    #pragma unroll
    for (int grp = 0; grp < 14; ++grp)
        A[grp] = *(const short8*)&wb[(grp * COUT + cf * 16 + s) * 32 + g * 8];

    // ---- stage x halo: 18 rows x 132 chunks, OOB rows -> zeros ----
    const uint4* xt4 = (const uint4*)xt;
    uint4* xs4 = (uint4*)xs;
    for (int i = t; i < 18 * XROW_CHUNKS; i += 512) {
        int row = i / XROW_CHUNKS, c = i - row * XROW_CHUNKS;
        int zdi = row / 6, rh = row - zdi * 6;
        int zd = d - 1 + zdi, zh = h0 - 1 + rh;
        uint4 v = {0u, 0u, 0u, 0u};
        if ((unsigned)zd < DD && (unsigned)zh < HH_)
            v = xt4[(size_t)((n * DD + zd) * HH_ + zh) * XROW_CHUNKS + c];
        xs4[i] = v;
    }
    __syncthreads();

    floatx4 acc[4];
    #pragma unroll
    for (int wf = 0; wf < 4; ++wf) acc[wf] = (floatx4){0.f, 0.f, 0.f, 0.f};

    int hbase = hq * XROW_U16 + s * 16 + (g & 1) * 8;

    #pragma unroll
    for (int grp = 0; grp < 14; ++grp) {
        const int qa = 2 * grp;
        const int qb = (grp == 13) ? 26 : 2 * grp + 1;
        const int t9a = qa / 3, t9b = qb / 3;
        const int ca = ((t9a / 3) * 6 + (t9a % 3)) * XROW_U16 + (qa % 3) * 16;
        const int cb = ((t9b / 3) * 6 + (t9b % 3)) * XROW_U16 + (qb % 3) * 16;
        int baddr = hbase + (ghi ? cb : ca);
        #pragma unroll
        for (int wf = 0; wf < 4; ++wf) {
            short8 B = *(const short8*)&xs[baddr + wf * 256];
            acc[wf] = __builtin_amdgcn_mfma_f32_16x16x32_bf16(A[grp], B, acc[wf], 0, 0, 0);
        }
    }

    // epilogue: C layout col = s -> w, row = g*4 + j -> co within cf half
    float s1[4], s2[4];
    #pragma unroll
    for (int j = 0; j < 4; ++j) { s1[j] = 0.f; s2[j] = 0.f; }
    #pragma unroll
    for (int j = 0; j < 4; ++j) {
        int co = cf * 16 + g * 4 + j;
        float bval = bias[co];
        size_t obase = ((size_t)(n * COUT + co) * DD + d) * (HH_ * WW_) + h * WW_ + s;
        #pragma unroll
        for (int wf = 0; wf < 4; ++wf) {
            float val = acc[wf][j] + bval;
            out[obase + wf * 16] = val;
            s1[j] += val;
            s2[j] += val * val;
        }
    }
    // reduce over the 16 s-lanes sharing each co
    #pragma unroll
    for (int m = 1; m < 16; m <<= 1) {
        #pragma unroll
        for (int j = 0; j < 4; ++j) {
            s1[j] += __shfl_xor(s1[j], m);
            s2[j] += __shfl_xor(s2[j], m);
        }
    }
    if (s == 0) {
        #pragma unroll
        for (int j = 0; j < 4; ++j) {
            int co = cf * 16 + g * 4 + j;
            sred[wv_][co]      = s1[j];
            sred[wv_][32 + co] = s2[j];
        }
    }
    __syncthreads();
    if (t < 64) {
        int cfh = (t >> 4) & 1;   // owner cf of column t (co = t&31)
        float v = sred[cfh][t] + sred[2 + cfh][t] + sred[4 + cfh][t] + sred[6 + cfh][t];
        atomicAdd(t < 32 ? &sums[t] : &sumsqs[t - 32], v);
    }
}

// ===================== FALLBACK PATH (fp32 VALU, round-2) =====================
#define WS_W      0
#define WS_SUM    13824
#define WS_SUMSQ  13856
#define WS_SCALE  13888
#define WS_SHIFT  13920

__global__ void prep_weights(const float* __restrict__ weight, float* __restrict__ ws) {
    int t = threadIdx.x;  // 512 threads
    if (t < 64) ws[WS_SUM + t] = 0.0f;
    int cout = t >> 4, cin = t & 15;
    const float* wp = weight + (cout * CIN + cin) * 27;
    float wv[27];
    float mx = -INFINITY;
    #pragma unroll
    for (int k = 0; k < 27; ++k) { wv[k] = wp[k]; mx = fmaxf(mx, wv[k]); }
    float cutoff = mx * 0.5f;
    const float win[3] = {0.08f, 1.0f, 0.08f};
    #pragma unroll
    for (int k = 0; k < 27; ++k) {
        float w = wv[k];
        float s = (w > 0.0f) ? 1.0f : ((w < 0.0f) ? -1.0f : 0.0f);
        float shr = s * fmaxf(fabsf(w) - cutoff * 0.01f, 0.0f);
        float o = (w < cutoff) ? shr : w;
        int kd = k / 9, kr = k % 9, kh = kr / 3, kw = kr % 3;
        o *= win[kd] * win[kh] * win[kw];
        ws[WS_W + (cin * 27 + k) * COUT + cout] = o;
    }
}

#define RS 68
__global__ __launch_bounds__(256, 4)
void conv_kernel(const float* __restrict__ x, const float* __restrict__ bias,
                 const float* __restrict__ wsw, float* __restrict__ out,
                 float* __restrict__ sums, float* __restrict__ sumsqs) {
    __shared__ float xsf[3 * 6 * RS];
    __shared__ float sredf[16][8];
    int b = blockIdx.x;
    int n  = b >> 8;
    int d  = (b >> 4) & 15;
    int h0 = (b & 15) << 2;
    int tid = threadIdx.x;
    int wg = tid & 15;
    int cg = (tid >> 4) & 3;
    int v  = tid >> 6;
    int cohalf = v & 1;
    int hhalf  = v >> 1;
    int w0 = wg * 4;
    int co0 = cohalf * 16 + cg * 4;
    float acc[4][2][4];
    #pragma unroll
    for (int c = 0; c < 4; ++c)
        #pragma unroll
        for (int i = 0; i < 2; ++i)
            #pragma unroll
            for (int j = 0; j < 4; ++j) acc[c][i][j] = 0.0f;
    const float* xn = x + (size_t)n * CIN * DD * HH_ * WW_;
    for (int cin = 0; cin < CIN; ++cin) {
        __syncthreads();
        const float* xc = xn + cin * DD * HH_ * WW_;
        for (int idx = tid; idx < 3 * 6 * RS; idx += 256) {
            int row = idx / RS;
            int c   = idx - row * RS;
            int dd  = row / 6;
            int r   = row - dd * 6;
            int zd = d - 1 + dd;
            int zh = h0 - 1 + r;
            int w  = c - 1;
            float val = 0.0f;
            if ((unsigned)zd < DD && (unsigned)zh < HH_ && (unsigned)w < WW_)
                val = xc[(zd * HH_ + zh) * WW_ + w];
            xsf[idx] = val;
        }
        __syncthreads();
        const float* wc = wsw + cin * 27 * COUT + co0;
        #pragma unroll 1
        for (int kd = 0; kd < 3; ++kd) {
            float4 wvv[9];
            #pragma unroll
            for (int j = 0; j < 9; ++j)
                wvv[j] = *(const float4*)&wc[(kd * 9 + j) * COUT];
            const float* xp = &xsf[(kd * 6 + hhalf * 2) * RS];
            #pragma unroll
            for (int rr = 0; rr < 4; ++rr) {
                const float* xr_ = &xp[rr * RS + w0];
                float4 xm = *(const float4*)xr_;
                float x4 = xr_[4];
                float x5 = xr_[5];
                float xv[6] = {xm.x, xm.y, xm.z, xm.w, x4, x5};
                #pragma unroll
                for (int kh = 0; kh < 3; ++kh) {
                    int i = rr - kh;
                    if (i < 0 || i > 1) continue;
                    #pragma unroll
                    for (int kw = 0; kw < 3; ++kw) {
                        float4 w4 = wvv[kh * 3 + kw];
                        #pragma unroll
                        for (int j = 0; j < 4; ++j) {
                            float xx = xv[j + kw];
                            acc[0][i][j] = fmaf(w4.x, xx, acc[0][i][j]);
                            acc[1][i][j] = fmaf(w4.y, xx, acc[1][i][j]);
                            acc[2][i][j] = fmaf(w4.z, xx, acc[2][i][j]);
                            acc[3][i][j] = fmaf(w4.w, xx, acc[3][i][j]);
                        }
                    }
                }
            }
        }
    }
    float s1[4], s2[4];
    #pragma unroll
    for (int c = 0; c < 4; ++c) {
        float bval = bias[co0 + c];
        s1[c] = 0.0f; s2[c] = 0.0f;
        #pragma unroll
        for (int i = 0; i < 2; ++i) {
            float4 o;
            float* op = (float*)&o;
            #pragma unroll
            for (int j = 0; j < 4; ++j) {
                float val = acc[c][i][j] + bval;
                op[j] = val;
                s1[c] += val;
                s2[c] += val * val;
            }
            int hh = h0 + hhalf * 2 + i;
            *(float4*)&out[((((size_t)n * COUT + co0 + c) * DD + d) * HH_ + hh) * WW_ + w0] = o;
        }
    }
    #pragma unroll
    for (int m = 1; m < 16; m <<= 1) {
        #pragma unroll
        for (int c = 0; c < 4; ++c) {
            s1[c] += __shfl_xor(s1[c], m);
            s2[c] += __shfl_xor(s2[c], m);
        }
    }
    if ((tid & 15) == 0) {
        int gg = tid >> 4;
        #pragma unroll
        for (int c = 0; c < 4; ++c) { sredf[gg][c] = s1[c]; sredf[gg][4 + c] = s2[c]; }
    }
    __syncthreads();
    if (tid < 64) {
        int co   = tid & 31;
        int kind = tid >> 5;
        int ch   = (co >> 4) & 1;
        int cgg  = (co >> 2) & 3;
        int c    = co & 3;
        float val = sredf[ch * 4 + cgg][kind * 4 + c] + sredf[(ch + 2) * 4 + cgg][kind * 4 + c];
        atomicAdd(kind ? &sumsqs[co] : &sums[co], val);
    }
}

// ===================== SHARED EPILOGUE KERNELS =====================
__global__ void stats_kernel(const float* __restrict__ gamma, const float* __restrict__ beta,
                             const float* __restrict__ sums, const float* __restrict__ sumsqs,
                             float* __restrict__ scale, float* __restrict__ shift) {
    int c = threadIdx.x;
    if (c >= 32) return;
    float mean = sums[c] / MCNT;
    float var  = sumsqs[c] / MCNT - mean * mean;
    float rstd = rsqrtf(var + 1e-5f);
    float sc = gamma[c] * rstd;
    scale[c] = sc;
    shift[c] = beta[c] - mean * sc;
}

__global__ void bn_act_kernel(float* __restrict__ out, const float* __restrict__ scale,
                              const float* __restrict__ shift) {
    const int NV4 = (N_ * COUT * DD * HH_ * WW_) / 4;
    int stride = gridDim.x * blockDim.x;
    float4* o4 = (float4*)out;
    for (int i = blockIdx.x * blockDim.x + threadIdx.x; i < NV4; i += stride) {
        int ch = (i >> 14) & 31;
        float sc = scale[ch];
        float sh = shift[ch];
        float4 val = o4[i];
        float* vp = (float*)&val;
        #pragma unroll
        for (int j = 0; j < 4; ++j) {
            float z = vp[j] * sc + sh;
            vp[j] = fmaxf(z, 0.0f) + log1pf(expf(-fabsf(z)));
        }
        o4[i] = val;
    }
}

extern "C" void kernel_launch(void* const* d_in, const int* in_sizes, int n_in,
                              void* d_out, int out_size, void* d_ws, size_t ws_size,
                              hipStream_t stream) {
    const float* x      = (const float*)d_in[0];
    const float* weight = (const float*)d_in[1];
    const float* bias   = (const float*)d_in[2];
    const float* gamma  = (const float*)d_in[3];
    const float* beta   = (const float*)d_in[4];
    float* out = (float*)d_out;
    float* wsf = (float*)d_ws;

    if (ws_size >= FAST_BYTES) {
        ushort* xt    = (ushort*)(wsf + FAST_XT_F);
        ushort* wb    = (ushort*)(wsf + FAST_WB_F);
        float*  stats = wsf + FAST_STAT_F;
        float*  sums   = stats;
        float*  sumsqs = stats + 32;
        float*  scale  = stats + 64;
        float*  shift  = stats + 96;
        hipLaunchKernelGGL(prep_weights_mfma, dim3(1), dim3(512), 0, stream, weight, wb, stats);
        hipLaunchKernelGGL(transpose_x, dim3(1024), dim3(256), 0, stream, x, xt);
        hipLaunchKernelGGL(conv_mfma, dim3(1024), dim3(512), 0, stream,
                           xt, wb, bias, out, sums, sumsqs);
        hipLaunchKernelGGL(stats_kernel, dim3(1), dim3(64), 0, stream,
                           gamma, beta, sums, sumsqs, scale, shift);
        hipLaunchKernelGGL(bn_act_kernel, dim3(2048), dim3(256), 0, stream, out, scale, shift);
    } else {
        hipLaunchKernelGGL(prep_weights, dim3(1), dim3(512), 0, stream, weight, wsf);
        hipLaunchKernelGGL(conv_kernel, dim3(1024), dim3(256), 0, stream,
                           x, bias, wsf + WS_W, out, wsf + WS_SUM, wsf + WS_SUMSQ);
        hipLaunchKernelGGL(stats_kernel, dim3(1), dim3(64), 0, stream,
                           gamma, beta, wsf + WS_SUM, wsf + WS_SUMSQ, wsf + WS_SCALE, wsf + WS_SHIFT);
        hipLaunchKernelGGL(bn_act_kernel, dim3(2048), dim3(256), 0, stream,
                           out, wsf + WS_SCALE, wsf + WS_SHIFT);
    }
}

// Round 8
// 65.509 us; speedup vs baseline: 6.9501x; 1.1881x over previous
//
#include <hip/hip_runtime.h>
#include <math.h>

#define N_    4
#define CIN   16
#define COUT  32
#define DD    16
#define HH_   64
#define WW_   64
#define MCNT  262144.0f   // per-channel count: 4*16*64*64

typedef __attribute__((ext_vector_type(8))) short short8;
typedef __attribute__((ext_vector_type(4))) float floatx4;

__device__ __forceinline__ ushort f2bf(float f) {
    uint u = __float_as_uint(f);
    uint r = (u + 0x7fffu + ((u >> 16) & 1u)) >> 16;
    return (ushort)r;
}

// ===================== FAST PATH (bf16 MFMA) =====================
// ws layout (float units):
//   [0, 2162688)            xT bf16 [4n][16d][64h][66 wslot][16 ci]  (4,325,376 u16)
//                           wslot = w+1; slots 0 and 65 are zeros
//   [2162688, 2169856)      wpk bf16 [14 grp][32 co][32 k]           (14,336 u16)
//                           group g packs (tap,kw) combos q=2g (k<16) and q=2g+1 (k>=16);
//                           q = (kd*3+kh)*3+kw; grp 13 upper half = zeros
//   [2169856, 2169920)      scale[32] shift[32]
//   [2169920, 2235456)      part[1024 blk][64]  (sum[32] ++ sumsq[32] per block)
#define FAST_XT_F    0
#define FAST_WB_F    2162688
#define FAST_SC_F    2169856
#define FAST_PART_F  2169920
#define FAST_BYTES   ((size_t)(FAST_PART_F + 65536) * 4)
#define XROW_U16     1056   // 66 slots * 16 ci
#define XROW_CHUNKS  132    // 16B chunks per row

// ---- weight preprocessing: soft-threshold + hamming + packed bf16 layout ----
__global__ void prep_weights_mfma(const float* __restrict__ weight,
                                  ushort* __restrict__ wb) {
    int t = threadIdx.x;  // 512 threads
    int cout = t >> 4, cin = t & 15;
    const float* wp = weight + (cout * CIN + cin) * 27;
    float wv[27];
    float mx = -INFINITY;
    #pragma unroll
    for (int k = 0; k < 27; ++k) { wv[k] = wp[k]; mx = fmaxf(mx, wv[k]); }
    float cutoff = mx * 0.5f;
    const float win[3] = {0.08f, 1.0f, 0.08f};
    #pragma unroll
    for (int k = 0; k < 27; ++k) {
        float w = wv[k];
        float s = (w > 0.0f) ? 1.0f : ((w < 0.0f) ? -1.0f : 0.0f);
        float shr = s * fmaxf(fabsf(w) - cutoff * 0.01f, 0.0f);
        float o = (w < cutoff) ? shr : w;
        int kd = k / 9, kr = k % 9, kh = kr / 3, kw = kr % 3;
        o *= win[kd] * win[kh] * win[kw];
        int q = (kd * 3 + kh) * 3 + kw;       // 0..26
        int grp = q >> 1, half = q & 1;
        wb[(grp * COUT + cout) * 32 + half * 16 + cin] = f2bf(o);
    }
    // zero upper half of group 13
    wb[(13 * COUT + cout) * 32 + 16 + cin] = 0;
}

// ---- x transpose: [n][ci][d][h][w] fp32 -> [n][d][h][wslot][ci] bf16 ----
__global__ __launch_bounds__(256, 4)
void transpose_x(const float* __restrict__ x, ushort* __restrict__ xt) {
    __shared__ ushort lds[4 * 64 * 16];
    int b = blockIdx.x;             // 1024 = n(4) x d(16) x hq(16)
    int n = b >> 8, d = (b >> 4) & 15, h0 = (b & 15) * 4;
    int t = threadIdx.x;
    int hh = t >> 6, w = t & 63;
    const float* xp = x + ((size_t)(n * CIN * DD + d) * HH_ + (h0 + hh)) * WW_ + w;
    const int CSTRIDE = DD * HH_ * WW_;  // 65536
    uint rowv[8];
    #pragma unroll
    for (int cp = 0; cp < 8; ++cp) {
        float a  = xp[(2 * cp)     * CSTRIDE];
        float b2 = xp[(2 * cp + 1) * CSTRIDE];
        rowv[cp] = (uint)f2bf(a) | ((uint)f2bf(b2) << 16);
    }
    #pragma unroll
    for (int cp = 0; cp < 8; ++cp)
        *(uint*)&lds[(hh * 64 + w) * 16 + 2 * cp] = rowv[cp];
    __syncthreads();
    uint* xtg = (uint*)xt;
    for (int i = t; i < 4 * 528; i += 256) {   // 528 u32 per h-row (66 slots x 8)
        int hh2 = i / 528, u = i - hh2 * 528;
        int slot = u >> 3, cp = u & 7;
        uint val = 0;
        if (slot >= 1 && slot <= 64)
            val = *(uint*)&lds[(hh2 * 64 + (slot - 1)) * 16 + 2 * cp];
        xtg[(size_t)((n * DD + d) * HH_ + (h0 + hh2)) * 528 + u] = val;
    }
}

// ---- conv via MFMA: A in registers (cf-split waves), x tile in LDS ----
// Grid: 1024 = n(4) x d(16) x ht(16 tiles of 4 h). Block: 512 threads, 8 waves.
// Wave wv = (hq<<1)|cf: h = h0+hq, couts cf*16..cf*16+15.
// Lane: s = l&15 (w within 16-group / A co row), g = l>>4 (k-group).
// Partial BN stats: NO global atomics — one private 256B store per block.
__global__ __launch_bounds__(512, 4)
void conv_mfma(const ushort* __restrict__ xt, const ushort* __restrict__ wb,
               const float* __restrict__ bias, float* __restrict__ out,
               float* __restrict__ part) {
    __shared__ ushort xs[3 * 6 * XROW_U16];   // 38016 B: [zdi][rh][66 slot][16 ci]
    __shared__ float sred[8][64];

    int b = blockIdx.x;
    int n = b >> 8, d = (b >> 4) & 15, h0 = (b & 15) * 4;
    int t = threadIdx.x;
    int l = t & 63;
    int wv_ = t >> 6;
    int hq = wv_ >> 1, cf = wv_ & 1;
    int h = h0 + hq;
    int s = l & 15, g = l >> 4;
    int ghi = g >> 1;                // 0: k<16 half, 1: k>=16 half

    // zero sred (each wave writes only its cf-half later; reader must see 0 elsewhere)
    ((float*)sred)[t] = 0.0f;

    // ---- A fragments: 14 x 16B from global (L2-hot 28.7 KB) ----
    short8 A[14];
    #pragma unroll
    for (int grp = 0; grp < 14; ++grp)
        A[grp] = *(const short8*)&wb[(grp * COUT + cf * 16 + s) * 32 + g * 8];

    // ---- stage x halo: 18 rows x 132 chunks, OOB rows -> zeros ----
    const uint4* xt4 = (const uint4*)xt;
    uint4* xs4 = (uint4*)xs;
    for (int i = t; i < 18 * XROW_CHUNKS; i += 512) {
        int row = i / XROW_CHUNKS, c = i - row * XROW_CHUNKS;
        int zdi = row / 6, rh = row - zdi * 6;
        int zd = d - 1 + zdi, zh = h0 - 1 + rh;
        uint4 v = {0u, 0u, 0u, 0u};
        if ((unsigned)zd < DD && (unsigned)zh < HH_)
            v = xt4[(size_t)((n * DD + zd) * HH_ + zh) * XROW_CHUNKS + c];
        xs4[i] = v;
    }
    __syncthreads();

    floatx4 acc[4];
    #pragma unroll
    for (int wf = 0; wf < 4; ++wf) acc[wf] = (floatx4){0.f, 0.f, 0.f, 0.f};

    int hbase = hq * XROW_U16 + s * 16 + (g & 1) * 8;

    #pragma unroll
    for (int grp = 0; grp < 14; ++grp) {
        const int qa = 2 * grp;
        const int qb = (grp == 13) ? 26 : 2 * grp + 1;
        const int t9a = qa / 3, t9b = qb / 3;
        const int ca = ((t9a / 3) * 6 + (t9a % 3)) * XROW_U16 + (qa % 3) * 16;
        const int cb = ((t9b / 3) * 6 + (t9b % 3)) * XROW_U16 + (qb % 3) * 16;
        int baddr = hbase + (ghi ? cb : ca);
        #pragma unroll
        for (int wf = 0; wf < 4; ++wf) {
            short8 B = *(const short8*)&xs[baddr + wf * 256];
            acc[wf] = __builtin_amdgcn_mfma_f32_16x16x32_bf16(A[grp], B, acc[wf], 0, 0, 0);
        }
    }

    // epilogue: C layout col = s -> w, row = g*4 + j -> co within cf half
    float s1[4], s2[4];
    #pragma unroll
    for (int j = 0; j < 4; ++j) { s1[j] = 0.f; s2[j] = 0.f; }
    #pragma unroll
    for (int j = 0; j < 4; ++j) {
        int co = cf * 16 + g * 4 + j;
        float bval = bias[co];
        size_t obase = ((size_t)(n * COUT + co) * DD + d) * (HH_ * WW_) + h * WW_ + s;
        #pragma unroll
        for (int wf = 0; wf < 4; ++wf) {
            float val = acc[wf][j] + bval;
            out[obase + wf * 16] = val;
            s1[j] += val;
            s2[j] += val * val;
        }
    }
    // reduce over the 16 s-lanes sharing each co
    #pragma unroll
    for (int m = 1; m < 16; m <<= 1) {
        #pragma unroll
        for (int j = 0; j < 4; ++j) {
            s1[j] += __shfl_xor(s1[j], m);
            s2[j] += __shfl_xor(s2[j], m);
        }
    }
    if (s == 0) {
        #pragma unroll
        for (int j = 0; j < 4; ++j) {
            int co = cf * 16 + g * 4 + j;
            sred[wv_][co]      = s1[j];
            sred[wv_][32 + co] = s2[j];
        }
    }
    __syncthreads();
    if (t < 64) {
        int cfh = (t >> 4) & 1;   // owner cf of column t (co = t&31)
        float v = sred[cfh][t] + sred[2 + cfh][t] + sred[4 + cfh][t] + sred[6 + cfh][t];
        part[(size_t)b * 64 + t] = v;   // private slot: no contention
    }
}

// ---- reduce part[1024][64] -> scale/shift (single block) ----
__global__ __launch_bounds__(1024)
void stats_fast(const float* __restrict__ part, const float* __restrict__ gamma,
                const float* __restrict__ beta, float* __restrict__ scale,
                float* __restrict__ shift) {
    __shared__ float red[16][64];
    __shared__ float tot[64];
    int t = threadIdx.x;
    int c = t & 63, rg = t >> 6;       // 16 row-groups x 64 blocks each
    const float* p = part + (size_t)rg * 64 * 64 + c;
    float s = 0.f;
    #pragma unroll 8
    for (int b = 0; b < 64; ++b) s += p[b * 64];
    red[rg][c] = s;
    __syncthreads();
    if (t < 64) {
        float v = 0.f;
        #pragma unroll
        for (int r = 0; r < 16; ++r) v += red[r][t];
        tot[t] = v;
    }
    __syncthreads();
    if (t < 32) {
        float mean = tot[t] / MCNT;
        float var  = tot[32 + t] / MCNT - mean * mean;
        float rstd = rsqrtf(var + 1e-5f);
        float sc = gamma[t] * rstd;
        scale[t] = sc;
        shift[t] = beta[t] - mean * sc;
    }
}

// ===================== FALLBACK PATH (fp32 VALU, round-2) =====================
#define WS_W      0
#define WS_SUM    13824
#define WS_SUMSQ  13856
#define WS_SCALE  13888
#define WS_SHIFT  13920

__global__ void prep_weights(const float* __restrict__ weight, float* __restrict__ ws) {
    int t = threadIdx.x;  // 512 threads
    if (t < 64) ws[WS_SUM + t] = 0.0f;
    int cout = t >> 4, cin = t & 15;
    const float* wp = weight + (cout * CIN + cin) * 27;
    float wv[27];
    float mx = -INFINITY;
    #pragma unroll
    for (int k = 0; k < 27; ++k) { wv[k] = wp[k]; mx = fmaxf(mx, wv[k]); }
    float cutoff = mx * 0.5f;
    const float win[3] = {0.08f, 1.0f, 0.08f};
    #pragma unroll
    for (int k = 0; k < 27; ++k) {
        float w = wv[k];
        float s = (w > 0.0f) ? 1.0f : ((w < 0.0f) ? -1.0f : 0.0f);
        float shr = s * fmaxf(fabsf(w) - cutoff * 0.01f, 0.0f);
        float o = (w < cutoff) ? shr : w;
        int kd = k / 9, kr = k % 9, kh = kr / 3, kw = kr % 3;
        o *= win[kd] * win[kh] * win[kw];
        ws[WS_W + (cin * 27 + k) * COUT + cout] = o;
    }
}

#define RS 68
__global__ __launch_bounds__(256, 4)
void conv_kernel(const float* __restrict__ x, const float* __restrict__ bias,
                 const float* __restrict__ wsw, float* __restrict__ out,
                 float* __restrict__ sums, float* __restrict__ sumsqs) {
    __shared__ float xsf[3 * 6 * RS];
    __shared__ float sredf[16][8];
    int b = blockIdx.x;
    int n  = b >> 8;
    int d  = (b >> 4) & 15;
    int h0 = (b & 15) << 2;
    int tid = threadIdx.x;
    int wg = tid & 15;
    int cg = (tid >> 4) & 3;
    int v  = tid >> 6;
    int cohalf = v & 1;
    int hhalf  = v >> 1;
    int w0 = wg * 4;
    int co0 = cohalf * 16 + cg * 4;
    float acc[4][2][4];
    #pragma unroll
    for (int c = 0; c < 4; ++c)
        #pragma unroll
        for (int i = 0; i < 2; ++i)
            #pragma unroll
            for (int j = 0; j < 4; ++j) acc[c][i][j] = 0.0f;
    const float* xn = x + (size_t)n * CIN * DD * HH_ * WW_;
    for (int cin = 0; cin < CIN; ++cin) {
        __syncthreads();
        const float* xc = xn + cin * DD * HH_ * WW_;
        for (int idx = tid; idx < 3 * 6 * RS; idx += 256) {
            int row = idx / RS;
            int c   = idx - row * RS;
            int dd  = row / 6;
            int r   = row - dd * 6;
            int zd = d - 1 + dd;
            int zh = h0 - 1 + r;
            int w  = c - 1;
            float val = 0.0f;
            if ((unsigned)zd < DD && (unsigned)zh < HH_ && (unsigned)w < WW_)
                val = xc[(zd * HH_ + zh) * WW_ + w];
            xsf[idx] = val;
        }
        __syncthreads();
        const float* wc = wsw + cin * 27 * COUT + co0;
        #pragma unroll 1
        for (int kd = 0; kd < 3; ++kd) {
            float4 wvv[9];
            #pragma unroll
            for (int j = 0; j < 9; ++j)
                wvv[j] = *(const float4*)&wc[(kd * 9 + j) * COUT];
            const float* xp = &xsf[(kd * 6 + hhalf * 2) * RS];
            #pragma unroll
            for (int rr = 0; rr < 4; ++rr) {
                const float* xr_ = &xp[rr * RS + w0];
                float4 xm = *(const float4*)xr_;
                float x4 = xr_[4];
                float x5 = xr_[5];
                float xv[6] = {xm.x, xm.y, xm.z, xm.w, x4, x5};
                #pragma unroll
                for (int kh = 0; kh < 3; ++kh) {
                    int i = rr - kh;
                    if (i < 0 || i > 1) continue;
                    #pragma unroll
                    for (int kw = 0; kw < 3; ++kw) {
                        float4 w4 = wvv[kh * 3 + kw];
                        #pragma unroll
                        for (int j = 0; j < 4; ++j) {
                            float xx = xv[j + kw];
                            acc[0][i][j] = fmaf(w4.x, xx, acc[0][i][j]);
                            acc[1][i][j] = fmaf(w4.y, xx, acc[1][i][j]);
                            acc[2][i][j] = fmaf(w4.z, xx, acc[2][i][j]);
                            acc[3][i][j] = fmaf(w4.w, xx, acc[3][i][j]);
                        }
                    }
                }
            }
        }
    }
    float s1[4], s2[4];
    #pragma unroll
    for (int c = 0; c < 4; ++c) {
        float bval = bias[co0 + c];
        s1[c] = 0.0f; s2[c] = 0.0f;
        #pragma unroll
        for (int i = 0; i < 2; ++i) {
            float4 o;
            float* op = (float*)&o;
            #pragma unroll
            for (int j = 0; j < 4; ++j) {
                float val = acc[c][i][j] + bval;
                op[j] = val;
                s1[c] += val;
                s2[c] += val * val;
            }
            int hh = h0 + hhalf * 2 + i;
            *(float4*)&out[((((size_t)n * COUT + co0 + c) * DD + d) * HH_ + hh) * WW_ + w0] = o;
        }
    }
    #pragma unroll
    for (int m = 1; m < 16; m <<= 1) {
        #pragma unroll
        for (int c = 0; c < 4; ++c) {
            s1[c] += __shfl_xor(s1[c], m);
            s2[c] += __shfl_xor(s2[c], m);
        }
    }
    if ((tid & 15) == 0) {
        int gg = tid >> 4;
        #pragma unroll
        for (int c = 0; c < 4; ++c) { sredf[gg][c] = s1[c]; sredf[gg][4 + c] = s2[c]; }
    }
    __syncthreads();
    if (tid < 64) {
        int co   = tid & 31;
        int kind = tid >> 5;
        int ch   = (co >> 4) & 1;
        int cgg  = (co >> 2) & 3;
        int c    = co & 3;
        float val = sredf[ch * 4 + cgg][kind * 4 + c] + sredf[(ch + 2) * 4 + cgg][kind * 4 + c];
        atomicAdd(kind ? &sumsqs[co] : &sums[co], val);
    }
}

// ===================== SHARED EPILOGUE KERNELS =====================
__global__ void stats_kernel(const float* __restrict__ gamma, const float* __restrict__ beta,
                             const float* __restrict__ sums, const float* __restrict__ sumsqs,
                             float* __restrict__ scale, float* __restrict__ shift) {
    int c = threadIdx.x;
    if (c >= 32) return;
    float mean = sums[c] / MCNT;
    float var  = sumsqs[c] / MCNT - mean * mean;
    float rstd = rsqrtf(var + 1e-5f);
    float sc = gamma[c] * rstd;
    scale[c] = sc;
    shift[c] = beta[c] - mean * sc;
}

__global__ void bn_act_kernel(float* __restrict__ out, const float* __restrict__ scale,
                              const float* __restrict__ shift) {
    const int NV4 = (N_ * COUT * DD * HH_ * WW_) / 4;
    int stride = gridDim.x * blockDim.x;
    float4* o4 = (float4*)out;
    for (int i = blockIdx.x * blockDim.x + threadIdx.x; i < NV4; i += stride) {
        int ch = (i >> 14) & 31;
        float sc = scale[ch];
        float sh = shift[ch];
        float4 val = o4[i];
        float* vp = (float*)&val;
        #pragma unroll
        for (int j = 0; j < 4; ++j) {
            float z = vp[j] * sc + sh;
            vp[j] = fmaxf(z, 0.0f) + log1pf(expf(-fabsf(z)));
        }
        o4[i] = val;
    }
}

extern "C" void kernel_launch(void* const* d_in, const int* in_sizes, int n_in,
                              void* d_out, int out_size, void* d_ws, size_t ws_size,
                              hipStream_t stream) {
    const float* x      = (const float*)d_in[0];
    const float* weight = (const float*)d_in[1];
    const float* bias   = (const float*)d_in[2];
    const float* gamma  = (const float*)d_in[3];
    const float* beta   = (const float*)d_in[4];
    float* out = (float*)d_out;
    float* wsf = (float*)d_ws;

    if (ws_size >= FAST_BYTES) {
        ushort* xt    = (ushort*)(wsf + FAST_XT_F);
        ushort* wb    = (ushort*)(wsf + FAST_WB_F);
        float*  scale = wsf + FAST_SC_F;
        float*  shift = wsf + FAST_SC_F + 32;
        float*  part  = wsf + FAST_PART_F;
        hipLaunchKernelGGL(prep_weights_mfma, dim3(1), dim3(512), 0, stream, weight, wb);
        hipLaunchKernelGGL(transpose_x, dim3(1024), dim3(256), 0, stream, x, xt);
        hipLaunchKernelGGL(conv_mfma, dim3(1024), dim3(512), 0, stream,
                           xt, wb, bias, out, part);
        hipLaunchKernelGGL(stats_fast, dim3(1), dim3(1024), 0, stream,
                           part, gamma, beta, scale, shift);
        hipLaunchKernelGGL(bn_act_kernel, dim3(2048), dim3(256), 0, stream, out, scale, shift);
    } else {
        hipLaunchKernelGGL(prep_weights, dim3(1), dim3(512), 0, stream, weight, wsf);
        hipLaunchKernelGGL(conv_kernel, dim3(1024), dim3(256), 0, stream,
                           x, bias, wsf + WS_W, out, wsf + WS_SUM, wsf + WS_SUMSQ);
        hipLaunchKernelGGL(stats_kernel, dim3(1), dim3(64), 0, stream,
                           gamma, beta, wsf + WS_SUM, wsf + WS_SUMSQ, wsf + WS_SCALE, wsf + WS_SHIFT);
        hipLaunchKernelGGL(bn_act_kernel, dim3(2048), dim3(256), 0, stream,
                           out, wsf + WS_SCALE, wsf + WS_SHIFT);
    }
}